// Round 1
// baseline (126.402 us; speedup 1.0000x reference)
//
#include <hip/hip_runtime.h>
#include <math.h>

#define BB 256
#define LL 3
#define CC 8
#define VV 20
#define SS 32
#define DD 64

__device__ __forceinline__ float sigmoidf_(float x) { return 1.0f / (1.0f + __expf(-x)); }

// ---------------- K1: user preprocessing -> cce_u, vce_u ----------------
__global__ void user_pre(const float* __restrict__ E, const int* __restrict__ ucv,
                         const int* __restrict__ ucl, const float* __restrict__ Wc,
                         const float* __restrict__ Wv, float* __restrict__ cce_u,
                         float* __restrict__ vce_u) {
    int b = blockIdx.x, d = threadIdx.x;
    __shared__ float vc[CC][DD];
    __shared__ float vmean[DD];
    for (int c = 0; c < CC; c++) {
        float a = 0.0f;
        const int* iv = ucv + (b * CC + c) * VV;
        for (int v = 0; v < VV; v++) a += E[iv[v] * DD + d];
        vc[c][d] = a;
    }
    __syncthreads();
    float cacc = 0.0f, vm = 0.0f;
    for (int c = 0; c < CC; c++) {
        float m = 0.0f;
        for (int k = 0; k < DD; k++) m += vc[c][k] * Wc[k * DD + d];
        cacc += E[ucl[b * CC + c] * DD + d] + sigmoidf_(m);
        vm += vc[c][d];
    }
    cce_u[b * DD + d] = cacc * (1.0f / CC);
    vmean[d] = vm * (1.0f / CC);
    __syncthreads();
    float mv = 0.0f;
    for (int k = 0; k < DD; k++) mv += vmean[k] * Wv[k * DD + d];
    vce_u[b * DD + d] = sigmoidf_(mv);
}

// ---------------- K2: item preprocessing -> cce_i, ie ----------------
__global__ void item_pre(const float* __restrict__ E, const int* __restrict__ items,
                         const int* __restrict__ icl, float* __restrict__ cce,
                         float* __restrict__ ie_out) {
    int b = blockIdx.x, d = threadIdx.x;
    float ie = E[items[b] * DD + d];
    float m = 0.0f;
    for (int c = 1; c < CC; c++) m += E[icl[b * CC + c] * DD + d];
    m *= (1.0f / (CC - 1));
    cce[b * DD + d] = ie * (1.0f + m);
    ie_out[b * DD + d] = ie;
}

// ---------------- K3: dst[b][k] = sum_d Wm[k][d]*src[b][d]  (k<128) ----------------
__global__ void mat_vec(const float* __restrict__ Wm, const float* __restrict__ src,
                        float* __restrict__ dst) {
    int b = blockIdx.x, k = threadIdx.x;  // 128 threads
    __shared__ float s[DD];
    if (k < DD) s[k] = src[b * DD + k];
    __syncthreads();
    float a = 0.0f;
    const float* wr = Wm + k * DD;
    for (int d = 0; d < DD; d++) a += wr[d] * s[d];
    dst[b * 128 + k] = a;
}

// ---------------- K4: fused _layer_emb per (b,l,c) group ----------------
template <bool HAS_P2>
__global__ void layer_emb(const float* __restrict__ E, const float* __restrict__ R,
                          const int* __restrict__ ts, const float* __restrict__ Wcce,
                          const float* __restrict__ Whv, float* __restrict__ o_out) {
    int g = blockIdx.x;  // b*L*C + l*C + c
    int b = g / (LL * CC);
    int tid = threadIdx.x;  // 64
    const int tbase = g * 3 * SS;
    __shared__ float t_lds[SS][65];
    __shared__ float wc[128];
    __shared__ float wh[128];
    __shared__ float wsm[SS];
    wc[tid] = Wcce[b * 128 + tid];
    wc[tid + 64] = Wcce[b * 128 + tid + 64];
    if constexpr (HAS_P2) {
        wh[tid] = Whv[b * 128 + tid];
        wh[tid + 64] = Whv[b * 128 + tid + 64];
    }
    // stage t rows: 32 rows x 16 float4 (16 consecutive lanes per row -> coalesced)
    for (int it = 0; it < 8; ++it) {
        int idx = tid + it * 64;  // 0..511
        int row = idx >> 4, f = idx & 15;
        int tix = ts[tbase + 2 * SS + row];
        const float4 v = *reinterpret_cast<const float4*>(E + (long)tix * DD + f * 4);
        t_lds[row][f * 4 + 0] = v.x;
        t_lds[row][f * 4 + 1] = v.y;
        t_lds[row][f * 4 + 2] = v.z;
        t_lds[row][f * 4 + 3] = v.w;
    }
    __syncthreads();
    int s = tid & 31, half = tid >> 5;
    float acc1 = 0.0f, acc2 = 0.0f;
    if (half == 0) {
        int hix = ts[tbase + s];
        const float* hrow = E + (long)hix * DD;
        for (int k = 0; k < DD; k++) {
            float hv = hrow[k];
            acc1 += hv * wc[k];
            if constexpr (HAS_P2) acc2 += hv * wh[k];
        }
    } else {
        int rix = ts[tbase + SS + s];
        const float* rrow = R + (long)rix * DD;
        for (int k = 0; k < DD; k++) {
            acc1 += rrow[k] * wc[64 + k];
            if constexpr (HAS_P2) acc2 += t_lds[s][k] * wh[64 + k];
        }
    }
    acc1 += __shfl_xor(acc1, 32, 64);
    if constexpr (HAS_P2) acc2 += __shfl_xor(acc2, 32, 64);
    float sg = sigmoidf_(acc1);
    float mx = sg;
    for (int m = 16; m > 0; m >>= 1) mx = fmaxf(mx, __shfl_xor(mx, m, 64));
    float e = __expf(sg - mx);
    float se = e;
    for (int m = 16; m > 0; m >>= 1) se += __shfl_xor(se, m, 64);
    float w = e / se;
    if constexpr (HAS_P2) w *= sigmoidf_(acc2);
    if (tid < 32) wsm[s] = w;
    __syncthreads();
    float o = 0.0f;
    for (int ss = 0; ss < SS; ++ss) o += wsm[ss] * t_lds[ss][tid];
    o_out[(long)g * DD + tid] = o;
}

// ---------------- K5: user aggregate ----------------
__global__ void post_user(const float* __restrict__ o_u, float* __restrict__ u) {
    int b = blockIdx.x, d = threadIdx.x;
    float acc = 0.0f;
    for (int lc = 0; lc < LL * CC; ++lc) {
        float x = o_u[(long)(b * LL * CC + lc) * DD + d];
        float ss = x * x;
        for (int m = 32; m > 0; m >>= 1) ss += __shfl_xor(ss, m, 64);
        acc += x / fmaxf(sqrtf(ss), 1e-12f);
    }
    u[b * DD + d] = acc * (1.0f / CC);
}

// ---------------- K6: item aggregate ----------------
__global__ void post_item(const float* __restrict__ o_i, const float* __restrict__ ie_buf,
                          float* __restrict__ out_c) {
    int b = blockIdx.x, d = threadIdx.x;
    float cs[CC];
    for (int c = 0; c < CC; c++) {
        float a = 0.0f;
        for (int l = 0; l < LL; l++) {
            float x = o_i[(long)((b * LL + l) * CC + c) * DD + d];
            float ss = x * x;
            for (int m = 32; m > 0; m >>= 1) ss += __shfl_xor(ss, m, 64);
            a += x / fmaxf(sqrtf(ss), 1e-12f);
        }
        cs[c] = a;
    }
    float p[CC - 1];
    float mx = -1e30f;
    for (int c = 0; c < CC - 1; c++) {
        float dd = cs[0] * cs[c + 1];
        for (int m = 32; m > 0; m >>= 1) dd += __shfl_xor(dd, m, 64);
        p[c] = sigmoidf_(dd);
        mx = fmaxf(mx, p[c]);
    }
    float se = 0.0f;
    for (int c = 0; c < CC - 1; c++) {
        p[c] = __expf(p[c] - mx);
        se += p[c];
    }
    float mean_cf = 0.0f;
    for (int c = 0; c < CC - 1; c++) mean_cf += (p[c] / se) * cs[c + 1];
    float ie = ie_buf[b * DD + d];
    float ad = ie * mean_cf;
    for (int m = 32; m > 0; m >>= 1) ad += __shfl_xor(ad, m, 64);
    float alpha = sigmoidf_(ad);
    out_c[b * DD + d] = alpha / (1.0f + alpha) * mean_cf + cs[0] + ie;
}

// ---------------- K7: final scores ----------------
__global__ void final_scores(const float* __restrict__ u, const float* __restrict__ ci,
                             const float* __restrict__ cn, float* __restrict__ out) {
    int b = blockIdx.x, d = threadIdx.x;
    float uv = u[b * DD + d];
    float s1 = uv * ci[b * DD + d];
    float s2 = uv * cn[b * DD + d];
    for (int m = 32; m > 0; m >>= 1) {
        s1 += __shfl_xor(s1, m, 64);
        s2 += __shfl_xor(s2, m, 64);
    }
    if (d == 0) {
        out[b] = s1;
        out[BB + b] = s2;
    }
}

extern "C" void kernel_launch(void* const* d_in, const int* in_sizes, int n_in,
                              void* d_out, int out_size, void* d_ws, size_t ws_size,
                              hipStream_t stream) {
    const int* ucv = (const int*)d_in[0];
    const int* items = (const int*)d_in[1];
    const int* negs = (const int*)d_in[2];
    const int* uts = (const int*)d_in[3];
    const int* its = (const int*)d_in[4];
    const int* nts = (const int*)d_in[5];
    const int* ucl = (const int*)d_in[6];
    const int* icl = (const int*)d_in[7];
    const int* ncl = (const int*)d_in[8];
    const float* E = (const float*)d_in[9];
    const float* R = (const float*)d_in[10];
    const float* W = (const float*)d_in[11];
    const float* W_ht = (const float*)d_in[12];
    const float* Wc = (const float*)d_in[13];
    const float* Wv = (const float*)d_in[14];

    float* ws = (float*)d_ws;
    float* cce_u = ws;                       // B*64
    float* vce_u = cce_u + BB * DD;          // B*64
    float* cce_i = vce_u + BB * DD;          // B*64
    float* cce_n = cce_i + BB * DD;          // B*64
    float* ie_i = cce_n + BB * DD;           // B*64
    float* ie_n = ie_i + BB * DD;            // B*64
    float* wcce_u = ie_n + BB * DD;          // B*128
    float* whv_u = wcce_u + BB * 128;        // B*128
    float* wcce_i = whv_u + BB * 128;        // B*128
    float* wcce_n = wcce_i + BB * 128;       // B*128
    float* o_u = wcce_n + BB * 128;          // B*L*C*64
    float* o_i = o_u + BB * LL * CC * DD;    // B*L*C*64
    float* o_n = o_i + BB * LL * CC * DD;    // B*L*C*64
    float* u = o_n + BB * LL * CC * DD;      // B*64
    float* ci = u + BB * DD;                 // B*64
    float* cn = ci + BB * DD;                // B*64

    user_pre<<<BB, 64, 0, stream>>>(E, ucv, ucl, Wc, Wv, cce_u, vce_u);
    item_pre<<<BB, 64, 0, stream>>>(E, items, icl, cce_i, ie_i);
    item_pre<<<BB, 64, 0, stream>>>(E, negs, ncl, cce_n, ie_n);
    mat_vec<<<BB, 128, 0, stream>>>(W, cce_u, wcce_u);
    mat_vec<<<BB, 128, 0, stream>>>(W_ht, vce_u, whv_u);
    mat_vec<<<BB, 128, 0, stream>>>(W, cce_i, wcce_i);
    mat_vec<<<BB, 128, 0, stream>>>(W, cce_n, wcce_n);
    layer_emb<true><<<BB * LL * CC, 64, 0, stream>>>(E, R, uts, wcce_u, whv_u, o_u);
    layer_emb<false><<<BB * LL * CC, 64, 0, stream>>>(E, R, its, wcce_i, nullptr, o_i);
    layer_emb<false><<<BB * LL * CC, 64, 0, stream>>>(E, R, nts, wcce_n, nullptr, o_n);
    post_user<<<BB, 64, 0, stream>>>(o_u, u);
    post_item<<<BB, 64, 0, stream>>>(o_i, ie_i, ci);
    post_item<<<BB, 64, 0, stream>>>(o_n, ie_n, cn);
    final_scores<<<BB, 64, 0, stream>>>(u, ci, cn, (float*)d_out);
}

// Round 2
// 92.750 us; speedup vs baseline: 1.3628x; 1.3628x over previous
//
#include <hip/hip_runtime.h>
#include <math.h>

#define BB 256
#define LL 3
#define CC 8
#define VV 20
#define SS 32
#define DD 64
#define NG (BB * LL * CC)  // 6144 groups per segment
#define TPAD 68            // float4-aligned, bank-shift 4 per row

__device__ __forceinline__ float sigmoidf_(float x) { return 1.0f / (1.0f + __expf(-x)); }
__device__ __forceinline__ float dot4_(float4 a, float4 b) {
    return a.x * b.x + a.y * b.y + a.z * b.z + a.w * b.w;
}

// ---------------- K1: fused prologue (per-b block, 128 threads) ----------------
// user_pre + item_pre(items) + item_pre(negs) + 4x mat_vec
__global__ __launch_bounds__(128) void prologue(
    const float* __restrict__ E, const int* __restrict__ ucv, const int* __restrict__ ucl,
    const int* __restrict__ items, const int* __restrict__ icl, const int* __restrict__ negs,
    const int* __restrict__ ncl, const float* __restrict__ W, const float* __restrict__ W_ht,
    const float* __restrict__ Wc, const float* __restrict__ Wv, float* __restrict__ wcce_u,
    float* __restrict__ whv_u, float* __restrict__ wcce_i, float* __restrict__ wcce_n,
    float* __restrict__ ie_i, float* __restrict__ ie_n) {
    int b = blockIdx.x, tid = threadIdx.x;
    int d = tid & 63, h = tid >> 6;  // h in {0,1}
    __shared__ float vc[CC][DD];
    __shared__ float part[2][DD];
    __shared__ float cce_u_s[DD], vce_u_s[DD], cce_i_s[DD], cce_n_s[DD], vmean_s[DD];

    // video sums per course (2 courses in parallel across halves)
    for (int c2 = 0; c2 < 4; ++c2) {
        int c = c2 * 2 + h;
        const int* iv = ucv + (b * CC + c) * VV;
        float a = 0.f;
        for (int v = 0; v < VV; ++v) a += E[(long)iv[v] * DD + d];
        vc[c][d] = a;
    }
    __syncthreads();
    // cce_u: sum_c E[ucl] + sigmoid(vc @ Wc)
    float cacc = 0.f;
    for (int c2 = 0; c2 < 4; ++c2) {
        int c = c2 * 2 + h;
        float m = 0.f;
        for (int k = 0; k < DD; ++k) m += vc[c][k] * Wc[k * DD + d];
        cacc += E[(long)ucl[b * CC + c] * DD + d] + sigmoidf_(m);
    }
    part[h][d] = cacc;
    __syncthreads();
    if (h == 0) {
        cce_u_s[d] = (part[0][d] + part[1][d]) * (1.f / CC);
        float vm = 0.f;
        for (int c = 0; c < CC; ++c) vm += vc[c][d];
        vmean_s[d] = vm * (1.f / CC);
    }
    __syncthreads();
    // vce_u = sigmoid(vmean @ Wv), k-range split across halves
    {
        float m = 0.f;
        for (int k = h * 32; k < h * 32 + 32; ++k) m += vmean_s[k] * Wv[k * DD + d];
        part[h][d] = m;
    }
    __syncthreads();
    if (h == 0) vce_u_s[d] = sigmoidf_(part[0][d] + part[1][d]);
    // item (h==0) and neg (h==1) preprocessing in parallel
    {
        const int* it = h ? negs : items;
        const int* cl = h ? ncl : icl;
        float* ies = h ? ie_n : ie_i;
        float* cces = h ? cce_n_s : cce_i_s;
        float ie = E[(long)it[b] * DD + d];
        float m = 0.f;
        for (int c = 1; c < CC; ++c) m += E[(long)cl[b * CC + c] * DD + d];
        m *= (1.f / (CC - 1));
        cces[d] = ie * (1.f + m);
        ies[b * DD + d] = ie;
    }
    __syncthreads();
    // 4 mat-vecs: thread k (0..127) computes row-k dot
    {
        float a0 = 0.f, a1 = 0.f, a2 = 0.f, a3 = 0.f;
        const float* wr = W + tid * DD;
        const float* wr2 = W_ht + tid * DD;
        for (int k = 0; k < DD; ++k) {
            float w = wr[k];
            a0 += w * cce_u_s[k];
            a2 += w * cce_i_s[k];
            a3 += w * cce_n_s[k];
            a1 += wr2[k] * vce_u_s[k];
        }
        wcce_u[b * 128 + tid] = a0;
        whv_u[b * 128 + tid] = a1;
        wcce_i[b * 128 + tid] = a2;
        wcce_n[b * 128 + tid] = a3;
    }
}

// ---------------- K2: mega layer_emb — 1 wave = 1 (seg,b,l,c) group ----------------
__global__ __launch_bounds__(256) void layer_all(
    const float* __restrict__ E, const float* __restrict__ R, const int* __restrict__ uts,
    const int* __restrict__ its, const int* __restrict__ nts, const float* __restrict__ wcce_u,
    const float* __restrict__ whv_u, const float* __restrict__ wcce_i,
    const float* __restrict__ wcce_n, float* __restrict__ o_all) {
    int tid = threadIdx.x;
    int w = tid >> 6;  // wave 0..3
    int lane = tid & 63;
    int f = lane & 15, grp = lane >> 4;  // 16 f-lanes x 4 row-groups
    int gg = blockIdx.x * 4 + w;
    int seg = gg / NG;
    int g = gg - seg * NG;
    int b = g / (LL * CC);
    const int* ts = (seg == 0) ? uts : (seg == 1) ? its : nts;
    const float* wcp = (seg == 0) ? wcce_u : (seg == 1) ? wcce_i : wcce_n;
    const bool has_p2 = (seg == 0);
    const long tbase = (long)g * 3 * SS;

    __shared__ float t_lds[4][SS][TPAD];
    __shared__ float s1_l[4][SS];
    __shared__ float s2_l[4][SS];
    __shared__ float wsm[4][SS];

    // per-lane W-fragments: lane f holds wc[4f..4f+3] etc. (register, no LDS)
    const float4* wc4 = (const float4*)(wcp + b * 128);
    float4 wc_h = wc4[f];
    float4 wc_r = wc4[f + 16];
    float4 wh_h = make_float4(0.f, 0.f, 0.f, 0.f), wh_t = wh_h;
    if (has_p2) {
        const float4* wh4 = (const float4*)(whv_u + b * 128);
        wh_h = wh4[f];
        wh_t = wh4[f + 16];
    }
#pragma unroll
    for (int p = 0; p < 8; ++p) {
        int row = p * 4 + grp;
        int hix = ts[tbase + row];
        int rix = ts[tbase + SS + row];
        int tix = ts[tbase + 2 * SS + row];
        float4 hv = *(const float4*)(E + (long)hix * DD + f * 4);
        float4 rv = *(const float4*)(R + (long)rix * DD + f * 4);
        float4 tv = *(const float4*)(E + (long)tix * DD + f * 4);
        *(float4*)(&t_lds[w][row][f * 4]) = tv;  // stage t while we have it
        float a1 = dot4_(hv, wc_h) + dot4_(rv, wc_r);
        float a2 = has_p2 ? (dot4_(hv, wh_h) + dot4_(tv, wh_t)) : 0.f;
#pragma unroll
        for (int m = 1; m < 16; m <<= 1) a1 += __shfl_xor(a1, m, 64);
        if (has_p2) {
#pragma unroll
            for (int m = 1; m < 16; m <<= 1) a2 += __shfl_xor(a2, m, 64);
        }
        if (f == 0) {
            s1_l[w][row] = a1;
            s2_l[w][row] = a2;
        }
    }
    __syncthreads();
    int s = lane & 31;
    float sg = sigmoidf_(s1_l[w][s]);
    float mx = sg;
#pragma unroll
    for (int m = 16; m > 0; m >>= 1) mx = fmaxf(mx, __shfl_xor(mx, m, 64));
    float e = __expf(sg - mx);
    float se = e;
#pragma unroll
    for (int m = 16; m > 0; m >>= 1) se += __shfl_xor(se, m, 64);
    float wgt = e / se;
    if (has_p2) wgt *= sigmoidf_(s2_l[w][s]);
    if (lane < 32) wsm[w][s] = wgt;
    __syncthreads();
    float o = 0.f;
#pragma unroll
    for (int ss2 = 0; ss2 < SS; ++ss2) o += wsm[w][ss2] * t_lds[w][ss2][lane];
    o_all[(long)gg * DD + lane] = o;
}

// ---------------- K3: fused postlude (per-b block, 3 waves) ----------------
__global__ __launch_bounds__(192) void postlude(const float* __restrict__ o_all,
                                                const float* __restrict__ ie_i,
                                                const float* __restrict__ ie_n,
                                                float* __restrict__ out) {
    int b = blockIdx.x, tid = threadIdx.x;
    int w = tid / 64, d = tid & 63;
    __shared__ float u_s[DD], ci_s[DD], cn_s[DD];
    if (w == 0) {
        const float* o_u = o_all + ((long)b * LL * CC) * DD;
        float acc = 0.f;
        for (int lc = 0; lc < LL * CC; ++lc) {
            float x = o_u[(long)lc * DD + d];
            float ss = x * x;
#pragma unroll
            for (int m = 32; m > 0; m >>= 1) ss += __shfl_xor(ss, m, 64);
            acc += x / fmaxf(sqrtf(ss), 1e-12f);
        }
        u_s[d] = acc * (1.f / CC);
    } else {
        const float* o_c = o_all + ((long)w * NG + (long)b * LL * CC) * DD;
        const float* ie_buf = (w == 1) ? ie_i : ie_n;
        float cs[CC];
        for (int c = 0; c < CC; ++c) {
            float a = 0.f;
            for (int l = 0; l < LL; ++l) {
                float x = o_c[(long)(l * CC + c) * DD + d];
                float ss = x * x;
#pragma unroll
                for (int m = 32; m > 0; m >>= 1) ss += __shfl_xor(ss, m, 64);
                a += x / fmaxf(sqrtf(ss), 1e-12f);
            }
            cs[c] = a;
        }
        float p[CC - 1];
        float mx = -1e30f;
        for (int c = 0; c < CC - 1; ++c) {
            float dd2 = cs[0] * cs[c + 1];
#pragma unroll
            for (int m = 32; m > 0; m >>= 1) dd2 += __shfl_xor(dd2, m, 64);
            p[c] = sigmoidf_(dd2);
            mx = fmaxf(mx, p[c]);
        }
        float se = 0.f;
        for (int c = 0; c < CC - 1; ++c) {
            p[c] = __expf(p[c] - mx);
            se += p[c];
        }
        float mcf = 0.f;
        for (int c = 0; c < CC - 1; ++c) mcf += (p[c] / se) * cs[c + 1];
        float ie = ie_buf[b * DD + d];
        float ad = ie * mcf;
#pragma unroll
        for (int m = 32; m > 0; m >>= 1) ad += __shfl_xor(ad, m, 64);
        float alpha = sigmoidf_(ad);
        float res = alpha / (1.f + alpha) * mcf + cs[0] + ie;
        if (w == 1)
            ci_s[d] = res;
        else
            cn_s[d] = res;
    }
    __syncthreads();
    if (w == 0) {
        float uv = u_s[d];
        float s1 = uv * ci_s[d];
        float s2 = uv * cn_s[d];
#pragma unroll
        for (int m = 32; m > 0; m >>= 1) {
            s1 += __shfl_xor(s1, m, 64);
            s2 += __shfl_xor(s2, m, 64);
        }
        if (d == 0) {
            out[b] = s1;
            out[BB + b] = s2;
        }
    }
}

extern "C" void kernel_launch(void* const* d_in, const int* in_sizes, int n_in,
                              void* d_out, int out_size, void* d_ws, size_t ws_size,
                              hipStream_t stream) {
    const int* ucv = (const int*)d_in[0];
    const int* items = (const int*)d_in[1];
    const int* negs = (const int*)d_in[2];
    const int* uts = (const int*)d_in[3];
    const int* its = (const int*)d_in[4];
    const int* nts = (const int*)d_in[5];
    const int* ucl = (const int*)d_in[6];
    const int* icl = (const int*)d_in[7];
    const int* ncl = (const int*)d_in[8];
    const float* E = (const float*)d_in[9];
    const float* R = (const float*)d_in[10];
    const float* W = (const float*)d_in[11];
    const float* W_ht = (const float*)d_in[12];
    const float* Wc = (const float*)d_in[13];
    const float* Wv = (const float*)d_in[14];

    float* ws = (float*)d_ws;
    float* wcce_u = ws;                   // B*128
    float* whv_u = wcce_u + BB * 128;     // B*128
    float* wcce_i = whv_u + BB * 128;     // B*128
    float* wcce_n = wcce_i + BB * 128;    // B*128
    float* ie_i = wcce_n + BB * 128;      // B*64
    float* ie_n = ie_i + BB * DD;         // B*64
    float* o_all = ie_n + BB * DD;        // 3*NG*64

    prologue<<<BB, 128, 0, stream>>>(E, ucv, ucl, items, icl, negs, ncl, W, W_ht, Wc, Wv,
                                     wcce_u, whv_u, wcce_i, wcce_n, ie_i, ie_n);
    layer_all<<<(3 * NG) / 4, 256, 0, stream>>>(E, R, uts, its, nts, wcce_u, whv_u, wcce_i,
                                                wcce_n, o_all);
    postlude<<<BB, 192, 0, stream>>>(o_all, ie_i, ie_n, (float*)d_out);
}

// Round 3
// 70.243 us; speedup vs baseline: 1.7995x; 1.3204x over previous
//
#include <hip/hip_runtime.h>
#include <math.h>

#define BB 256
#define LL 3
#define CC 8
#define VV 20
#define SS 32
#define DD 64
#define NG (BB * LL * CC)  // 6144 groups per segment

__device__ __forceinline__ float sigmoidf_(float x) { return 1.0f / (1.0f + __expf(-x)); }
__device__ __forceinline__ float dot4_(float4 a, float4 b) {
    return a.x * b.x + a.y * b.y + a.z * b.z + a.w * b.w;
}

// ---------------- K1: fused prologue (per-b block, 256 threads) ----------------
__global__ __launch_bounds__(256) void prologue(
    const float* __restrict__ E, const int* __restrict__ ucv, const int* __restrict__ ucl,
    const int* __restrict__ items, const int* __restrict__ icl, const int* __restrict__ negs,
    const int* __restrict__ ncl, const float* __restrict__ W, const float* __restrict__ W_ht,
    const float* __restrict__ Wc, const float* __restrict__ Wv, float* __restrict__ wcce_u,
    float* __restrict__ whv_u, float* __restrict__ wcce_i, float* __restrict__ wcce_n,
    float* __restrict__ ie_i, float* __restrict__ ie_n) {
    int b = blockIdx.x, tid = threadIdx.x;
    int d = tid & 63, q = tid >> 6;  // q in 0..3
    __shared__ float vcs[CC][DD];
    __shared__ float part[4][DD];
    __shared__ float part2[4][DD];
    __shared__ float cce_u_s[DD], vce_u_s[DD], cce_i_s[DD], cce_n_s[DD], vmean_s[DD];
    __shared__ float ie_s[2][DD];

    // Phase A: video sums for c in {q, q+4}; ucl gathers
    float p1 = 0.f;
    for (int cc = 0; cc < 2; ++cc) {
        int c = q + cc * 4;
        const int* iv = ucv + (b * CC + c) * VV;
        float a = 0.f;
#pragma unroll
        for (int v = 0; v < VV; ++v) a += E[(long)iv[v] * DD + d];
        vcs[c][d] = a;
        p1 += E[(long)ucl[b * CC + c] * DD + d];
    }
    part[q][d] = p1;
    __syncthreads();
    // Phase B: sigmoid(vc @ Wc) partials over same c set
    {
        float sacc = 0.f;
        for (int cc = 0; cc < 2; ++cc) {
            int c = q + cc * 4;
            float m = 0.f;
#pragma unroll 8
            for (int k = 0; k < DD; ++k) m += vcs[c][k] * Wc[k * DD + d];
            sacc += sigmoidf_(m);
        }
        part2[q][d] = sacc;
    }
    __syncthreads();
    if (q == 0) {
        float s = 0.f;
#pragma unroll
        for (int i = 0; i < 4; ++i) s += part[i][d] + part2[i][d];
        cce_u_s[d] = s * (1.f / CC);
        float vm = 0.f;
#pragma unroll
        for (int c = 0; c < CC; ++c) vm += vcs[c][d];
        vmean_s[d] = vm * (1.f / CC);
    }
    __syncthreads();
    // Phase C: vce partial (k-split 4 ways)
    {
        float m = 0.f;
        for (int k = q * 16; k < q * 16 + 16; ++k) m += vmean_s[k] * Wv[k * DD + d];
        part[q][d] = m;
    }
    // Phase D: item/neg course sums; q0: item c1..4, q1: item c5..7 + ie,
    //          q2: neg c1..4, q3: neg c5..7 + ie
    {
        const int* cl = (q < 2) ? icl : ncl;
        int c0 = (q & 1) ? 5 : 1, c1 = (q & 1) ? 8 : 5;
        float m = 0.f;
        for (int c = c0; c < c1; ++c) m += E[(long)cl[b * CC + c] * DD + d];
        part2[q][d] = m;
        if (q == 1) ie_s[0][d] = E[(long)items[b] * DD + d];
        if (q == 3) ie_s[1][d] = E[(long)negs[b] * DD + d];
    }
    __syncthreads();
    if (q == 0) {
        vce_u_s[d] = sigmoidf_(part[0][d] + part[1][d] + part[2][d] + part[3][d]);
        float ie = ie_s[0][d];
        cce_i_s[d] = ie * (1.f + (part2[0][d] + part2[1][d]) * (1.f / 7.f));
        ie_i[b * DD + d] = ie;
    } else if (q == 1) {
        float ie = ie_s[1][d];
        cce_n_s[d] = ie * (1.f + (part2[2][d] + part2[3][d]) * (1.f / 7.f));
        ie_n[b * DD + d] = ie;
    }
    __syncthreads();
    // Phase E: 4 mat-vecs (512 dots of len 64, 2 per thread)
    {
        int k = tid & 127, sel = tid >> 7;
        const float* wr = (sel ? W_ht : W) + k * DD;
        const float* wr2 = W + k * DD;
        const float* v1 = sel ? vce_u_s : cce_u_s;
        const float* v2 = sel ? cce_n_s : cce_i_s;
        float a = 0.f, c2 = 0.f;
#pragma unroll 8
        for (int kk = 0; kk < DD; ++kk) {
            a += wr[kk] * v1[kk];
            c2 += wr2[kk] * v2[kk];
        }
        if (sel == 0) {
            wcce_u[b * 128 + k] = a;
            wcce_i[b * 128 + k] = c2;
        } else {
            whv_u[b * 128 + k] = a;
            wcce_n[b * 128 + k] = c2;
        }
    }
}

// ---------------- K2: layer_emb, 1 wave = 1 group, no LDS, no barriers ----------------
// Writes NORMALIZED per-group o (normalize moved here from postlude).
__global__ __launch_bounds__(256) void layer_all(
    const float* __restrict__ E, const float* __restrict__ R, const int* __restrict__ uts,
    const int* __restrict__ its, const int* __restrict__ nts, const float* __restrict__ wcce_u,
    const float* __restrict__ whv_u, const float* __restrict__ wcce_i,
    const float* __restrict__ wcce_n, float* __restrict__ o_all) {
    int tid = threadIdx.x;
    int w = tid >> 6, lane = tid & 63;
    int f = lane & 15, grp = lane >> 4;  // 16 f-lanes x 4 row-groups
    int gg = blockIdx.x * 4 + w;
    int seg = gg / NG;
    int g = gg - seg * NG;
    int b = g / (LL * CC);
    const int* ts = (seg == 0) ? uts : (seg == 1) ? its : nts;
    const float* wcp = (seg == 0) ? wcce_u : (seg == 1) ? wcce_i : wcce_n;
    const bool has_p2 = (seg == 0);
    const int* tg = ts + (long)g * 3 * SS;

    const float4* wc4 = (const float4*)(wcp + b * 128);
    float4 wc_h = wc4[f], wc_r = wc4[f + 16];
    float4 wh_h = make_float4(0.f, 0.f, 0.f, 0.f), wh_t = wh_h;
    if (has_p2) {
        const float4* wh4 = (const float4*)(whv_u + b * 128);
        wh_h = wh4[f];
        wh_t = wh4[f + 16];
    }

    float4 tv[8];
    float s1[8], s2[8];
#pragma unroll
    for (int p = 0; p < 8; ++p) {
        int row = p * 4 + grp;
        int hix = tg[row], rix = tg[SS + row], tix = tg[2 * SS + row];
        float4 hv = *(const float4*)(E + (long)hix * DD + f * 4);
        float4 rv = *(const float4*)(R + (long)rix * DD + f * 4);
        float4 t4 = *(const float4*)(E + (long)tix * DD + f * 4);
        tv[p] = t4;
        float a1 = dot4_(hv, wc_h) + dot4_(rv, wc_r);
#pragma unroll
        for (int m = 1; m < 16; m <<= 1) a1 += __shfl_xor(a1, m, 64);
        s1[p] = a1;
        if (has_p2) {
            float a2 = dot4_(hv, wh_h) + dot4_(t4, wh_t);
#pragma unroll
            for (int m = 1; m < 16; m <<= 1) a2 += __shfl_xor(a2, m, 64);
            s2[p] = a2;
        }
    }
    // softmax over the 32 rows (8 per lane x 4 grps)
    float mx = -1e30f;
#pragma unroll
    for (int p = 0; p < 8; ++p) {
        s1[p] = sigmoidf_(s1[p]);
        mx = fmaxf(mx, s1[p]);
    }
    mx = fmaxf(mx, __shfl_xor(mx, 16, 64));
    mx = fmaxf(mx, __shfl_xor(mx, 32, 64));
    float se = 0.f;
#pragma unroll
    for (int p = 0; p < 8; ++p) {
        s1[p] = __expf(s1[p] - mx);
        se += s1[p];
    }
    se += __shfl_xor(se, 16, 64);
    se += __shfl_xor(se, 32, 64);
    float inv = 1.f / se;
    float4 oacc = make_float4(0.f, 0.f, 0.f, 0.f);
#pragma unroll
    for (int p = 0; p < 8; ++p) {
        float wgt = s1[p] * inv;
        if (has_p2) wgt *= sigmoidf_(s2[p]);
        oacc.x += wgt * tv[p].x;
        oacc.y += wgt * tv[p].y;
        oacc.z += wgt * tv[p].z;
        oacc.w += wgt * tv[p].w;
    }
    // cross-grp reduce (rows split over grps)
#pragma unroll
    for (int m = 16; m <= 32; m <<= 1) {
        oacc.x += __shfl_xor(oacc.x, m, 64);
        oacc.y += __shfl_xor(oacc.y, m, 64);
        oacc.z += __shfl_xor(oacc.z, m, 64);
        oacc.w += __shfl_xor(oacc.w, m, 64);
    }
    // normalize over d (within the 16 f-lanes; all grps hold identical copies)
    float qq = dot4_(oacc, oacc);
#pragma unroll
    for (int m = 1; m < 16; m <<= 1) qq += __shfl_xor(qq, m, 64);
    float innorm = 1.f / fmaxf(sqrtf(qq), 1e-12f);
    if (grp == 0) {
        oacc.x *= innorm;
        oacc.y *= innorm;
        oacc.z *= innorm;
        oacc.w *= innorm;
        *(float4*)(o_all + (long)gg * DD + f * 4) = oacc;
    }
}

// ---------------- K3: fused postlude (per-b block, 3 waves; o already normalized) -------
__global__ __launch_bounds__(192) void postlude(const float* __restrict__ o_all,
                                                const float* __restrict__ ie_i,
                                                const float* __restrict__ ie_n,
                                                float* __restrict__ out) {
    int b = blockIdx.x, tid = threadIdx.x;
    int w = tid / 64, d = tid & 63;
    __shared__ float u_s[DD], ci_s[DD], cn_s[DD];
    if (w == 0) {
        const float* o_u = o_all + (long)b * LL * CC * DD;
        float acc = 0.f;
#pragma unroll
        for (int lc = 0; lc < LL * CC; ++lc) acc += o_u[lc * DD + d];
        u_s[d] = acc * (1.f / CC);
    } else {
        const float* o_c = o_all + ((long)w * NG + (long)b * LL * CC) * DD;
        const float* ie_buf = (w == 1) ? ie_i : ie_n;
        float cs[CC];
#pragma unroll
        for (int c = 0; c < CC; ++c) {
            float a = 0.f;
#pragma unroll
            for (int l = 0; l < LL; ++l) a += o_c[(l * CC + c) * DD + d];
            cs[c] = a;
        }
        float p[CC - 1];
        float mx = -1e30f;
        for (int c = 0; c < CC - 1; ++c) {
            float dd2 = cs[0] * cs[c + 1];
#pragma unroll
            for (int m = 32; m > 0; m >>= 1) dd2 += __shfl_xor(dd2, m, 64);
            p[c] = sigmoidf_(dd2);
            mx = fmaxf(mx, p[c]);
        }
        float se = 0.f;
        for (int c = 0; c < CC - 1; ++c) {
            p[c] = __expf(p[c] - mx);
            se += p[c];
        }
        float mcf = 0.f;
        for (int c = 0; c < CC - 1; ++c) mcf += (p[c] / se) * cs[c + 1];
        float ie = ie_buf[b * DD + d];
        float ad = ie * mcf;
#pragma unroll
        for (int m = 32; m > 0; m >>= 1) ad += __shfl_xor(ad, m, 64);
        float alpha = sigmoidf_(ad);
        float res = alpha / (1.f + alpha) * mcf + cs[0] + ie;
        if (w == 1)
            ci_s[d] = res;
        else
            cn_s[d] = res;
    }
    __syncthreads();
    if (w == 0) {
        float uv = u_s[d];
        float s1 = uv * ci_s[d];
        float s2 = uv * cn_s[d];
#pragma unroll
        for (int m = 32; m > 0; m >>= 1) {
            s1 += __shfl_xor(s1, m, 64);
            s2 += __shfl_xor(s2, m, 64);
        }
        if (d == 0) {
            out[b] = s1;
            out[BB + b] = s2;
        }
    }
}

extern "C" void kernel_launch(void* const* d_in, const int* in_sizes, int n_in,
                              void* d_out, int out_size, void* d_ws, size_t ws_size,
                              hipStream_t stream) {
    const int* ucv = (const int*)d_in[0];
    const int* items = (const int*)d_in[1];
    const int* negs = (const int*)d_in[2];
    const int* uts = (const int*)d_in[3];
    const int* its = (const int*)d_in[4];
    const int* nts = (const int*)d_in[5];
    const int* ucl = (const int*)d_in[6];
    const int* icl = (const int*)d_in[7];
    const int* ncl = (const int*)d_in[8];
    const float* E = (const float*)d_in[9];
    const float* R = (const float*)d_in[10];
    const float* W = (const float*)d_in[11];
    const float* W_ht = (const float*)d_in[12];
    const float* Wc = (const float*)d_in[13];
    const float* Wv = (const float*)d_in[14];

    float* ws = (float*)d_ws;
    float* wcce_u = ws;                 // B*128
    float* whv_u = wcce_u + BB * 128;   // B*128
    float* wcce_i = whv_u + BB * 128;   // B*128
    float* wcce_n = wcce_i + BB * 128;  // B*128
    float* ie_i = wcce_n + BB * 128;    // B*64
    float* ie_n = ie_i + BB * DD;       // B*64
    float* o_all = ie_n + BB * DD;      // 3*NG*64

    prologue<<<BB, 256, 0, stream>>>(E, ucv, ucl, items, icl, negs, ncl, W, W_ht, Wc, Wv,
                                     wcce_u, whv_u, wcce_i, wcce_n, ie_i, ie_n);
    layer_all<<<(3 * NG) / 4, 256, 0, stream>>>(E, R, uts, its, nts, wcce_u, whv_u, wcce_i,
                                                wcce_n, o_all);
    postlude<<<BB, 192, 0, stream>>>(o_all, ie_i, ie_n, (float*)d_out);
}

// Round 4
// 64.016 us; speedup vs baseline: 1.9746x; 1.0973x over previous
//
#include <hip/hip_runtime.h>
#include <math.h>

#define BB 256
#define LL 3
#define CC 8
#define VV 20
#define SS 32
#define DD 64
#define NG (BB * LL * CC)  // 6144 groups per segment

__device__ __forceinline__ float sigmoidf_(float x) { return 1.0f / (1.0f + __expf(-x)); }
__device__ __forceinline__ float dot4_(float4 a, float4 b) {
    return a.x * b.x + a.y * b.y + a.z * b.z + a.w * b.w;
}

// ---------------- K1: fused prologue (per-b block, 256 threads) ----------------
__global__ __launch_bounds__(256) void prologue(
    const float* __restrict__ E, const int* __restrict__ ucv, const int* __restrict__ ucl,
    const int* __restrict__ items, const int* __restrict__ icl, const int* __restrict__ negs,
    const int* __restrict__ ncl, const float* __restrict__ W, const float* __restrict__ W_ht,
    const float* __restrict__ Wc, const float* __restrict__ Wv, float* __restrict__ wcce_u,
    float* __restrict__ whv_u, float* __restrict__ wcce_i, float* __restrict__ wcce_n,
    float* __restrict__ ie_i, float* __restrict__ ie_n) {
    int b = blockIdx.x, tid = threadIdx.x;
    int d = tid & 63, q = tid >> 6;  // q in 0..3
    __shared__ float vcs[CC][DD];
    __shared__ float part[4][DD];
    __shared__ float part2[4][DD];
    __shared__ float cce_u_s[DD], vce_u_s[DD], cce_i_s[DD], cce_n_s[DD], vmean_s[DD];
    __shared__ float ie_s[2][DD];

    // Phase A: video sums for c in {q, q+4}; ucl gathers
    float p1 = 0.f;
    for (int cc = 0; cc < 2; ++cc) {
        int c = q + cc * 4;
        const int* iv = ucv + (b * CC + c) * VV;
        float a = 0.f;
#pragma unroll
        for (int v = 0; v < VV; ++v) a += E[(long)iv[v] * DD + d];
        vcs[c][d] = a;
        p1 += E[(long)ucl[b * CC + c] * DD + d];
    }
    part[q][d] = p1;
    __syncthreads();
    // Phase B: sigmoid(vc @ Wc) partials over same c set
    {
        float sacc = 0.f;
        for (int cc = 0; cc < 2; ++cc) {
            int c = q + cc * 4;
            float m = 0.f;
#pragma unroll 8
            for (int k = 0; k < DD; ++k) m += vcs[c][k] * Wc[k * DD + d];
            sacc += sigmoidf_(m);
        }
        part2[q][d] = sacc;
    }
    __syncthreads();
    if (q == 0) {
        float s = 0.f;
#pragma unroll
        for (int i = 0; i < 4; ++i) s += part[i][d] + part2[i][d];
        cce_u_s[d] = s * (1.f / CC);
        float vm = 0.f;
#pragma unroll
        for (int c = 0; c < CC; ++c) vm += vcs[c][d];
        vmean_s[d] = vm * (1.f / CC);
    }
    __syncthreads();
    // Phase C: vce partial (k-split 4 ways)
    {
        float m = 0.f;
        for (int k = q * 16; k < q * 16 + 16; ++k) m += vmean_s[k] * Wv[k * DD + d];
        part[q][d] = m;
    }
    // Phase D: item/neg course sums
    {
        const int* cl = (q < 2) ? icl : ncl;
        int c0 = (q & 1) ? 5 : 1, c1 = (q & 1) ? 8 : 5;
        float m = 0.f;
        for (int c = c0; c < c1; ++c) m += E[(long)cl[b * CC + c] * DD + d];
        part2[q][d] = m;
        if (q == 1) ie_s[0][d] = E[(long)items[b] * DD + d];
        if (q == 3) ie_s[1][d] = E[(long)negs[b] * DD + d];
    }
    __syncthreads();
    if (q == 0) {
        vce_u_s[d] = sigmoidf_(part[0][d] + part[1][d] + part[2][d] + part[3][d]);
        float ie = ie_s[0][d];
        cce_i_s[d] = ie * (1.f + (part2[0][d] + part2[1][d]) * (1.f / 7.f));
        ie_i[b * DD + d] = ie;
    } else if (q == 1) {
        float ie = ie_s[1][d];
        cce_n_s[d] = ie * (1.f + (part2[2][d] + part2[3][d]) * (1.f / 7.f));
        ie_n[b * DD + d] = ie;
    }
    __syncthreads();
    // Phase E: 4 mat-vecs (512 dots of len 64, 2 per thread)
    {
        int k = tid & 127, sel = tid >> 7;
        const float* wr = (sel ? W_ht : W) + k * DD;
        const float* wr2 = W + k * DD;
        const float* v1 = sel ? vce_u_s : cce_u_s;
        const float* v2 = sel ? cce_n_s : cce_i_s;
        float a = 0.f, c2 = 0.f;
#pragma unroll 8
        for (int kk = 0; kk < DD; ++kk) {
            a += wr[kk] * v1[kk];
            c2 += wr2[kk] * v2[kk];
        }
        if (sel == 0) {
            wcce_u[b * 128 + k] = a;
            wcce_i[b * 128 + k] = c2;
        } else {
            whv_u[b * 128 + k] = a;
            wcce_n[b * 128 + k] = c2;
        }
    }
}

// ---------------- K2: layer_emb, 1 wave = 1 group; FULL PREFETCH for MLP ----------------
// All 24 gathers issued before any dependent compute -> 24 outstanding VMEM/wave.
__global__ __launch_bounds__(256, 3) void layer_all(
    const float* __restrict__ E, const float* __restrict__ R, const int* __restrict__ uts,
    const int* __restrict__ its, const int* __restrict__ nts, const float* __restrict__ wcce_u,
    const float* __restrict__ whv_u, const float* __restrict__ wcce_i,
    const float* __restrict__ wcce_n, float* __restrict__ o_all) {
    int tid = threadIdx.x;
    int w = tid >> 6, lane = tid & 63;
    int f = lane & 15, grp = lane >> 4;  // 16 f-lanes x 4 row-groups
    int gg = blockIdx.x * 4 + w;
    int seg = gg / NG;
    int g = gg - seg * NG;
    int b = g / (LL * CC);
    const int* ts = (seg == 0) ? uts : (seg == 1) ? its : nts;
    const float* wcp = (seg == 0) ? wcce_u : (seg == 1) ? wcce_i : wcce_n;
    const bool has_p2 = (seg == 0);
    const int* tg = ts + (long)g * 3 * SS;

    // ---- issue ALL index loads first ----
    int hix[8], rix[8], tix[8];
#pragma unroll
    for (int p = 0; p < 8; ++p) {
        int row = p * 4 + grp;
        hix[p] = tg[row];
        rix[p] = tg[SS + row];
        tix[p] = tg[2 * SS + row];
    }
    const float4* wc4 = (const float4*)(wcp + b * 128);
    float4 wc_h = wc4[f], wc_r = wc4[f + 16];
    float4 wh_h = make_float4(0.f, 0.f, 0.f, 0.f), wh_t = wh_h;
    if (has_p2) {
        const float4* wh4 = (const float4*)(whv_u + b * 128);
        wh_h = wh4[f];
        wh_t = wh4[f + 16];
    }
    // ---- issue ALL 24 row gathers (h, r, t) before any compute ----
    float4 hv[8], rv[8], t4[8];
#pragma unroll
    for (int p = 0; p < 8; ++p) hv[p] = *(const float4*)(E + (long)hix[p] * DD + f * 4);
#pragma unroll
    for (int p = 0; p < 8; ++p) rv[p] = *(const float4*)(R + (long)rix[p] * DD + f * 4);
#pragma unroll
    for (int p = 0; p < 8; ++p) t4[p] = *(const float4*)(E + (long)tix[p] * DD + f * 4);

    // ---- compute: dots + 16-lane reduces ----
    float s1[8], s2[8];
#pragma unroll
    for (int p = 0; p < 8; ++p) {
        float a1 = dot4_(hv[p], wc_h) + dot4_(rv[p], wc_r);
#pragma unroll
        for (int m = 1; m < 16; m <<= 1) a1 += __shfl_xor(a1, m, 64);
        s1[p] = a1;
    }
    if (has_p2) {
#pragma unroll
        for (int p = 0; p < 8; ++p) {
            float a2 = dot4_(hv[p], wh_h) + dot4_(t4[p], wh_t);
#pragma unroll
            for (int m = 1; m < 16; m <<= 1) a2 += __shfl_xor(a2, m, 64);
            s2[p] = a2;
        }
    }
    // softmax over the 32 rows (8 per lane-column x 4 grps)
    float mx = -1e30f;
#pragma unroll
    for (int p = 0; p < 8; ++p) {
        s1[p] = sigmoidf_(s1[p]);
        mx = fmaxf(mx, s1[p]);
    }
    mx = fmaxf(mx, __shfl_xor(mx, 16, 64));
    mx = fmaxf(mx, __shfl_xor(mx, 32, 64));
    float se = 0.f;
#pragma unroll
    for (int p = 0; p < 8; ++p) {
        s1[p] = __expf(s1[p] - mx);
        se += s1[p];
    }
    se += __shfl_xor(se, 16, 64);
    se += __shfl_xor(se, 32, 64);
    float inv = 1.f / se;
    float4 oacc = make_float4(0.f, 0.f, 0.f, 0.f);
#pragma unroll
    for (int p = 0; p < 8; ++p) {
        float wgt = s1[p] * inv;
        if (has_p2) wgt *= sigmoidf_(s2[p]);
        oacc.x += wgt * t4[p].x;
        oacc.y += wgt * t4[p].y;
        oacc.z += wgt * t4[p].z;
        oacc.w += wgt * t4[p].w;
    }
    // cross-grp reduce (rows split over grps)
#pragma unroll
    for (int m = 16; m <= 32; m <<= 1) {
        oacc.x += __shfl_xor(oacc.x, m, 64);
        oacc.y += __shfl_xor(oacc.y, m, 64);
        oacc.z += __shfl_xor(oacc.z, m, 64);
        oacc.w += __shfl_xor(oacc.w, m, 64);
    }
    // normalize over d (within the 16 f-lanes; all grps hold identical copies)
    float qq = dot4_(oacc, oacc);
#pragma unroll
    for (int m = 1; m < 16; m <<= 1) qq += __shfl_xor(qq, m, 64);
    float innorm = 1.f / fmaxf(sqrtf(qq), 1e-12f);
    if (grp == 0) {
        oacc.x *= innorm;
        oacc.y *= innorm;
        oacc.z *= innorm;
        oacc.w *= innorm;
        *(float4*)(o_all + (long)gg * DD + f * 4) = oacc;
    }
}

// ---------------- K3: fused postlude (per-b block, 3 waves; o already normalized) -------
__global__ __launch_bounds__(192) void postlude(const float* __restrict__ o_all,
                                                const float* __restrict__ ie_i,
                                                const float* __restrict__ ie_n,
                                                float* __restrict__ out) {
    int b = blockIdx.x, tid = threadIdx.x;
    int w = tid / 64, d = tid & 63;
    __shared__ float u_s[DD], ci_s[DD], cn_s[DD];
    if (w == 0) {
        const float* o_u = o_all + (long)b * LL * CC * DD;
        float acc = 0.f;
#pragma unroll
        for (int lc = 0; lc < LL * CC; ++lc) acc += o_u[lc * DD + d];
        u_s[d] = acc * (1.f / CC);
    } else {
        const float* o_c = o_all + ((long)w * NG + (long)b * LL * CC) * DD;
        const float* ie_buf = (w == 1) ? ie_i : ie_n;
        float cs[CC];
#pragma unroll
        for (int c = 0; c < CC; ++c) {
            float a = 0.f;
#pragma unroll
            for (int l = 0; l < LL; ++l) a += o_c[(l * CC + c) * DD + d];
            cs[c] = a;
        }
        float p[CC - 1];
        float mx = -1e30f;
        for (int c = 0; c < CC - 1; ++c) {
            float dd2 = cs[0] * cs[c + 1];
#pragma unroll
            for (int m = 32; m > 0; m >>= 1) dd2 += __shfl_xor(dd2, m, 64);
            p[c] = sigmoidf_(dd2);
            mx = fmaxf(mx, p[c]);
        }
        float se = 0.f;
        for (int c = 0; c < CC - 1; ++c) {
            p[c] = __expf(p[c] - mx);
            se += p[c];
        }
        float mcf = 0.f;
        for (int c = 0; c < CC - 1; ++c) mcf += (p[c] / se) * cs[c + 1];
        float ie = ie_buf[b * DD + d];
        float ad = ie * mcf;
#pragma unroll
        for (int m = 32; m > 0; m >>= 1) ad += __shfl_xor(ad, m, 64);
        float alpha = sigmoidf_(ad);
        float res = alpha / (1.f + alpha) * mcf + cs[0] + ie;
        if (w == 1)
            ci_s[d] = res;
        else
            cn_s[d] = res;
    }
    __syncthreads();
    if (w == 0) {
        float uv = u_s[d];
        float s1 = uv * ci_s[d];
        float s2 = uv * cn_s[d];
#pragma unroll
        for (int m = 32; m > 0; m >>= 1) {
            s1 += __shfl_xor(s1, m, 64);
            s2 += __shfl_xor(s2, m, 64);
        }
        if (d == 0) {
            out[b] = s1;
            out[BB + b] = s2;
        }
    }
}

extern "C" void kernel_launch(void* const* d_in, const int* in_sizes, int n_in,
                              void* d_out, int out_size, void* d_ws, size_t ws_size,
                              hipStream_t stream) {
    const int* ucv = (const int*)d_in[0];
    const int* items = (const int*)d_in[1];
    const int* negs = (const int*)d_in[2];
    const int* uts = (const int*)d_in[3];
    const int* its = (const int*)d_in[4];
    const int* nts = (const int*)d_in[5];
    const int* ucl = (const int*)d_in[6];
    const int* icl = (const int*)d_in[7];
    const int* ncl = (const int*)d_in[8];
    const float* E = (const float*)d_in[9];
    const float* R = (const float*)d_in[10];
    const float* W = (const float*)d_in[11];
    const float* W_ht = (const float*)d_in[12];
    const float* Wc = (const float*)d_in[13];
    const float* Wv = (const float*)d_in[14];

    float* ws = (float*)d_ws;
    float* wcce_u = ws;                 // B*128
    float* whv_u = wcce_u + BB * 128;   // B*128
    float* wcce_i = whv_u + BB * 128;   // B*128
    float* wcce_n = wcce_i + BB * 128;  // B*128
    float* ie_i = wcce_n + BB * 128;    // B*64
    float* ie_n = ie_i + BB * DD;       // B*64
    float* o_all = ie_n + BB * DD;      // 3*NG*64

    prologue<<<BB, 256, 0, stream>>>(E, ucv, ucl, items, icl, negs, ncl, W, W_ht, Wc, Wv,
                                     wcce_u, whv_u, wcce_i, wcce_n, ie_i, ie_n);
    layer_all<<<(3 * NG) / 4, 256, 0, stream>>>(E, R, uts, its, nts, wcce_u, whv_u, wcce_i,
                                                wcce_n, o_all);
    postlude<<<BB, 192, 0, stream>>>(o_all, ie_i, ie_n, (float*)d_out);
}

// Round 5
// 63.759 us; speedup vs baseline: 1.9825x; 1.0040x over previous
//
#include <hip/hip_runtime.h>
#include <math.h>

#define BB 256
#define LL 3
#define CC 8
#define VV 20
#define SS 32
#define DD 64
#define NG (BB * LL * CC)  // 6144 groups per segment

__device__ __forceinline__ float sigmoidf_(float x) { return 1.0f / (1.0f + __expf(-x)); }
__device__ __forceinline__ float dot4_(float4 a, float4 b) {
    return a.x * b.x + a.y * b.y + a.z * b.z + a.w * b.w;
}

// ---------------- K1: fused prologue (per-b block, 256 threads) ----------------
__global__ __launch_bounds__(256) void prologue(
    const float* __restrict__ E, const int* __restrict__ ucv, const int* __restrict__ ucl,
    const int* __restrict__ items, const int* __restrict__ icl, const int* __restrict__ negs,
    const int* __restrict__ ncl, const float* __restrict__ W, const float* __restrict__ W_ht,
    const float* __restrict__ Wc, const float* __restrict__ Wv, float* __restrict__ wcce_u,
    float* __restrict__ whv_u, float* __restrict__ wcce_i, float* __restrict__ wcce_n,
    float* __restrict__ ie_i, float* __restrict__ ie_n) {
    int b = blockIdx.x, tid = threadIdx.x;
    int d = tid & 63, q = tid >> 6;  // q in 0..3
    __shared__ float vcs[CC][DD];
    __shared__ float part[4][DD];
    __shared__ float part2[4][DD];
    __shared__ float cce_u_s[DD], vce_u_s[DD], cce_i_s[DD], cce_n_s[DD], vmean_s[DD];
    __shared__ float ie_s[2][DD];

    // Phase A: video sums for c in {q, q+4}; ucl gathers
    float p1 = 0.f;
    for (int cc = 0; cc < 2; ++cc) {
        int c = q + cc * 4;
        const int* iv = ucv + (b * CC + c) * VV;
        float a = 0.f;
#pragma unroll
        for (int v = 0; v < VV; ++v) a += E[(long)iv[v] * DD + d];
        vcs[c][d] = a;
        p1 += E[(long)ucl[b * CC + c] * DD + d];
    }
    part[q][d] = p1;
    __syncthreads();
    // Phase B: sigmoid(vc @ Wc) partials over same c set
    {
        float sacc = 0.f;
        for (int cc = 0; cc < 2; ++cc) {
            int c = q + cc * 4;
            float m = 0.f;
#pragma unroll 8
            for (int k = 0; k < DD; ++k) m += vcs[c][k] * Wc[k * DD + d];
            sacc += sigmoidf_(m);
        }
        part2[q][d] = sacc;
    }
    __syncthreads();
    if (q == 0) {
        float s = 0.f;
#pragma unroll
        for (int i = 0; i < 4; ++i) s += part[i][d] + part2[i][d];
        cce_u_s[d] = s * (1.f / CC);
        float vm = 0.f;
#pragma unroll
        for (int c = 0; c < CC; ++c) vm += vcs[c][d];
        vmean_s[d] = vm * (1.f / CC);
    }
    __syncthreads();
    // Phase C: vce partial (k-split 4 ways)
    {
        float m = 0.f;
        for (int k = q * 16; k < q * 16 + 16; ++k) m += vmean_s[k] * Wv[k * DD + d];
        part[q][d] = m;
    }
    // Phase D: item/neg course sums
    {
        const int* cl = (q < 2) ? icl : ncl;
        int c0 = (q & 1) ? 5 : 1, c1 = (q & 1) ? 8 : 5;
        float m = 0.f;
        for (int c = c0; c < c1; ++c) m += E[(long)cl[b * CC + c] * DD + d];
        part2[q][d] = m;
        if (q == 1) ie_s[0][d] = E[(long)items[b] * DD + d];
        if (q == 3) ie_s[1][d] = E[(long)negs[b] * DD + d];
    }
    __syncthreads();
    if (q == 0) {
        vce_u_s[d] = sigmoidf_(part[0][d] + part[1][d] + part[2][d] + part[3][d]);
        float ie = ie_s[0][d];
        cce_i_s[d] = ie * (1.f + (part2[0][d] + part2[1][d]) * (1.f / 7.f));
        ie_i[b * DD + d] = ie;
    } else if (q == 1) {
        float ie = ie_s[1][d];
        cce_n_s[d] = ie * (1.f + (part2[2][d] + part2[3][d]) * (1.f / 7.f));
        ie_n[b * DD + d] = ie;
    }
    __syncthreads();
    // Phase E: 4 mat-vecs (512 dots of len 64, 2 per thread)
    {
        int k = tid & 127, sel = tid >> 7;
        const float* wr = (sel ? W_ht : W) + k * DD;
        const float* wr2 = W + k * DD;
        const float* v1 = sel ? vce_u_s : cce_u_s;
        const float* v2 = sel ? cce_n_s : cce_i_s;
        float a = 0.f, c2 = 0.f;
#pragma unroll 8
        for (int kk = 0; kk < DD; ++kk) {
            a += wr[kk] * v1[kk];
            c2 += wr2[kk] * v2[kk];
        }
        if (sel == 0) {
            wcce_u[b * 128 + k] = a;
            wcce_i[b * 128 + k] = c2;
        } else {
            whv_u[b * 128 + k] = a;
            wcce_n[b * 128 + k] = c2;
        }
    }
}

// ---------------- K2: layer_emb, 1 wave = 1 group; sched_barrier-pinned MLP -------------
// All 24 row gathers are FORCED to issue before any dependent compute via
// __builtin_amdgcn_sched_barrier(0) fences (the scheduler otherwise sinks each
// load next to its use — R4 showed VGPR=56, i.e. fully serialized gathers).
__global__ __launch_bounds__(256, 3) void layer_all(
    const float* __restrict__ E, const float* __restrict__ R, const int* __restrict__ uts,
    const int* __restrict__ its, const int* __restrict__ nts, const float* __restrict__ wcce_u,
    const float* __restrict__ whv_u, const float* __restrict__ wcce_i,
    const float* __restrict__ wcce_n, float* __restrict__ o_all) {
    int tid = threadIdx.x;
    int w = tid >> 6, lane = tid & 63;
    int f = lane & 15, grp = lane >> 4;  // 16 f-lanes x 4 row-groups
    int gg = blockIdx.x * 4 + w;
    int seg = gg / NG;
    int g = gg - seg * NG;
    int b = g / (LL * CC);
    const int* ts = (seg == 0) ? uts : (seg == 1) ? its : nts;
    const float* wcp = (seg == 0) ? wcce_u : (seg == 1) ? wcce_i : wcce_n;
    const bool has_p2 = (seg == 0);
    const int* tg = ts + (long)g * 3 * SS;

    // ---- issue all index loads + w-fragment loads ----
    int hix[8], rix[8], tix[8];
#pragma unroll
    for (int p = 0; p < 8; ++p) {
        int row = p * 4 + grp;
        hix[p] = tg[row];
        rix[p] = tg[SS + row];
        tix[p] = tg[2 * SS + row];
    }
    const float4* wc4 = (const float4*)(wcp + b * 128);
    float4 wc_h = wc4[f], wc_r = wc4[f + 16];
    float4 wh_h = make_float4(0.f, 0.f, 0.f, 0.f), wh_t = wh_h;
    if (has_p2) {
        const float4* wh4 = (const float4*)(whv_u + b * 128);
        wh_h = wh4[f];
        wh_t = wh4[f + 16];
    }
    __builtin_amdgcn_sched_barrier(0);
    // ---- issue ALL 24 row gathers before any compute (pinned) ----
    float4 hv[8], rv[8], t4[8];
#pragma unroll
    for (int p = 0; p < 8; ++p) hv[p] = *(const float4*)(E + (long)hix[p] * DD + f * 4);
#pragma unroll
    for (int p = 0; p < 8; ++p) rv[p] = *(const float4*)(R + (long)rix[p] * DD + f * 4);
#pragma unroll
    for (int p = 0; p < 8; ++p) t4[p] = *(const float4*)(E + (long)tix[p] * DD + f * 4);
    __builtin_amdgcn_sched_barrier(0);

    // ---- compute: dots + 16-lane reduces (consumes loads in issue order) ----
    float s1[8], s2[8];
#pragma unroll
    for (int p = 0; p < 8; ++p) {
        float a1 = dot4_(hv[p], wc_h) + dot4_(rv[p], wc_r);
#pragma unroll
        for (int m = 1; m < 16; m <<= 1) a1 += __shfl_xor(a1, m, 64);
        s1[p] = a1;
    }
    if (has_p2) {
#pragma unroll
        for (int p = 0; p < 8; ++p) {
            float a2 = dot4_(hv[p], wh_h) + dot4_(t4[p], wh_t);
#pragma unroll
            for (int m = 1; m < 16; m <<= 1) a2 += __shfl_xor(a2, m, 64);
            s2[p] = a2;
        }
    }
    // softmax over the 32 rows (8 per lane-column x 4 grps)
    float mx = -1e30f;
#pragma unroll
    for (int p = 0; p < 8; ++p) {
        s1[p] = sigmoidf_(s1[p]);
        mx = fmaxf(mx, s1[p]);
    }
    mx = fmaxf(mx, __shfl_xor(mx, 16, 64));
    mx = fmaxf(mx, __shfl_xor(mx, 32, 64));
    float se = 0.f;
#pragma unroll
    for (int p = 0; p < 8; ++p) {
        s1[p] = __expf(s1[p] - mx);
        se += s1[p];
    }
    se += __shfl_xor(se, 16, 64);
    se += __shfl_xor(se, 32, 64);
    float inv = 1.f / se;
    float4 oacc = make_float4(0.f, 0.f, 0.f, 0.f);
#pragma unroll
    for (int p = 0; p < 8; ++p) {
        float wgt = s1[p] * inv;
        if (has_p2) wgt *= sigmoidf_(s2[p]);
        oacc.x += wgt * t4[p].x;
        oacc.y += wgt * t4[p].y;
        oacc.z += wgt * t4[p].z;
        oacc.w += wgt * t4[p].w;
    }
    // cross-grp reduce (rows split over grps)
#pragma unroll
    for (int m = 16; m <= 32; m <<= 1) {
        oacc.x += __shfl_xor(oacc.x, m, 64);
        oacc.y += __shfl_xor(oacc.y, m, 64);
        oacc.z += __shfl_xor(oacc.z, m, 64);
        oacc.w += __shfl_xor(oacc.w, m, 64);
    }
    // normalize over d (within the 16 f-lanes; all grps hold identical copies)
    float qq = dot4_(oacc, oacc);
#pragma unroll
    for (int m = 1; m < 16; m <<= 1) qq += __shfl_xor(qq, m, 64);
    float innorm = 1.f / fmaxf(sqrtf(qq), 1e-12f);
    if (grp == 0) {
        oacc.x *= innorm;
        oacc.y *= innorm;
        oacc.z *= innorm;
        oacc.w *= innorm;
        *(float4*)(o_all + (long)gg * DD + f * 4) = oacc;
    }
}

// ---------------- K3: fused postlude (per-b block, 3 waves; o already normalized) -------
__global__ __launch_bounds__(192) void postlude(const float* __restrict__ o_all,
                                                const float* __restrict__ ie_i,
                                                const float* __restrict__ ie_n,
                                                float* __restrict__ out) {
    int b = blockIdx.x, tid = threadIdx.x;
    int w = tid / 64, d = tid & 63;
    __shared__ float u_s[DD], ci_s[DD], cn_s[DD];
    if (w == 0) {
        const float* o_u = o_all + (long)b * LL * CC * DD;
        float acc = 0.f;
#pragma unroll
        for (int lc = 0; lc < LL * CC; ++lc) acc += o_u[lc * DD + d];
        u_s[d] = acc * (1.f / CC);
    } else {
        const float* o_c = o_all + ((long)w * NG + (long)b * LL * CC) * DD;
        const float* ie_buf = (w == 1) ? ie_i : ie_n;
        float cs[CC];
#pragma unroll
        for (int c = 0; c < CC; ++c) {
            float a = 0.f;
#pragma unroll
            for (int l = 0; l < LL; ++l) a += o_c[(l * CC + c) * DD + d];
            cs[c] = a;
        }
        float p[CC - 1];
        float mx = -1e30f;
        for (int c = 0; c < CC - 1; ++c) {
            float dd2 = cs[0] * cs[c + 1];
#pragma unroll
            for (int m = 32; m > 0; m >>= 1) dd2 += __shfl_xor(dd2, m, 64);
            p[c] = sigmoidf_(dd2);
            mx = fmaxf(mx, p[c]);
        }
        float se = 0.f;
        for (int c = 0; c < CC - 1; ++c) {
            p[c] = __expf(p[c] - mx);
            se += p[c];
        }
        float mcf = 0.f;
        for (int c = 0; c < CC - 1; ++c) mcf += (p[c] / se) * cs[c + 1];
        float ie = ie_buf[b * DD + d];
        float ad = ie * mcf;
#pragma unroll
        for (int m = 32; m > 0; m >>= 1) ad += __shfl_xor(ad, m, 64);
        float alpha = sigmoidf_(ad);
        float res = alpha / (1.f + alpha) * mcf + cs[0] + ie;
        if (w == 1)
            ci_s[d] = res;
        else
            cn_s[d] = res;
    }
    __syncthreads();
    if (w == 0) {
        float uv = u_s[d];
        float s1 = uv * ci_s[d];
        float s2 = uv * cn_s[d];
#pragma unroll
        for (int m = 32; m > 0; m >>= 1) {
            s1 += __shfl_xor(s1, m, 64);
            s2 += __shfl_xor(s2, m, 64);
        }
        if (d == 0) {
            out[b] = s1;
            out[BB + b] = s2;
        }
    }
}

extern "C" void kernel_launch(void* const* d_in, const int* in_sizes, int n_in,
                              void* d_out, int out_size, void* d_ws, size_t ws_size,
                              hipStream_t stream) {
    const int* ucv = (const int*)d_in[0];
    const int* items = (const int*)d_in[1];
    const int* negs = (const int*)d_in[2];
    const int* uts = (const int*)d_in[3];
    const int* its = (const int*)d_in[4];
    const int* nts = (const int*)d_in[5];
    const int* ucl = (const int*)d_in[6];
    const int* icl = (const int*)d_in[7];
    const int* ncl = (const int*)d_in[8];
    const float* E = (const float*)d_in[9];
    const float* R = (const float*)d_in[10];
    const float* W = (const float*)d_in[11];
    const float* W_ht = (const float*)d_in[12];
    const float* Wc = (const float*)d_in[13];
    const float* Wv = (const float*)d_in[14];

    float* ws = (float*)d_ws;
    float* wcce_u = ws;                 // B*128
    float* whv_u = wcce_u + BB * 128;   // B*128
    float* wcce_i = whv_u + BB * 128;   // B*128
    float* wcce_n = wcce_i + BB * 128;  // B*128
    float* ie_i = wcce_n + BB * 128;    // B*64
    float* ie_n = ie_i + BB * DD;       // B*64
    float* o_all = ie_n + BB * DD;      // 3*NG*64

    prologue<<<BB, 256, 0, stream>>>(E, ucv, ucl, items, icl, negs, ncl, W, W_ht, Wc, Wv,
                                     wcce_u, whv_u, wcce_i, wcce_n, ie_i, ie_n);
    layer_all<<<(3 * NG) / 4, 256, 0, stream>>>(E, R, uts, its, nts, wcce_u, whv_u, wcce_i,
                                                wcce_n, o_all);
    postlude<<<BB, 192, 0, stream>>>(o_all, ie_i, ie_n, (float*)d_out);
}